// Round 1
// baseline (404.014 us; speedup 1.0000x reference)
//
#include <hip/hip_runtime.h>

// DeformableConv2D: B=4, H=W=56, CIN=64, FILTERS=64, NDG=4, KS=3, fp32.
// Fused single kernel: offset conv + bilinear deform sampling + grouped conv.
// Block = 256 threads = 4 waves; each wave owns one output pixel.

#define NB   4
#define NH   56
#define NW   56
#define NC   64        // CIN
#define NDG  4
#define NK   9         // taps (3x3)
#define NKG  36        // NK * NDG
#define NOFF 72        // NKG * 2 offset channels
#define NF   64        // FILTERS
#define PPB  4         // pixels (waves) per block
#define PADMAXF 57.0f  // padded-coord clip upper bound (in_h-1 = 58-1)
#define PSTRIDE 68     // NC + 4 pad: groups g=0..3 land on distinct LDS banks

__global__ __launch_bounds__(256, 3)
void dcn_fused(const float* __restrict__ xin,    // [4,56,56,64]
               const float* __restrict__ offk,   // [3,3,64,72]  (HWIO)
               const float* __restrict__ offb,   // [72]
               const float* __restrict__ wk,     // [3,3,64,64]  (ki,kj,f,cin)
               float* __restrict__ out)          // [4,56,56,64]
{
    __shared__ float s_x[PPB][NK * NC];          // 3x3 neighborhood per pixel
    __shared__ float s_off[PPB][NOFF];           // predicted offsets per pixel
    __shared__ float s_pix[PPB][NKG][PSTRIDE];   // bilinear-sampled pixels

    const int tid  = threadIdx.x;
    const int wv   = tid >> 6;     // wave id == pixel slot
    const int lane = tid & 63;

    const int pix0 = blockIdx.x * PPB;
    const int pix  = pix0 + wv;
    const int b    = pix / (NH * NW);
    const int rr   = pix - b * NH * NW;
    const int oh   = rr / NW;
    const int ow   = rr - oh * NW;

    // ---- stage 3x3 input neighborhood (lane = channel, coalesced) ----
    #pragma unroll
    for (int t = 0; t < NK; ++t) {
        const int ih = oh + (t / 3) - 1;
        const int iw = ow + (t % 3) - 1;
        float v = 0.0f;
        if (ih >= 0 && ih < NH && iw >= 0 && iw < NW)
            v = xin[(((b * NH) + ih) * NW + iw) * NC + lane];
        s_x[wv][t * NC + lane] = v;
    }
    __syncthreads();

    // ---- phase 0: offset-prediction conv (PPB*72 = 288 outputs / 256 thr) ----
    for (int idx = tid; idx < PPB * NOFF; idx += 256) {
        const int p  = idx / NOFF;
        const int oc = idx - p * NOFF;
        float a0 = offb[oc], a1 = 0.0f, a2 = 0.0f, a3 = 0.0f;
        for (int t = 0; t < NK; ++t) {
            const float* kp = offk + (t * NC) * NOFF + oc;  // stride NOFF over c
            const float* xp = &s_x[p][t * NC];              // broadcast reads
            #pragma unroll 4
            for (int c = 0; c < NC; c += 4) {
                a0 = fmaf(xp[c + 0], kp[(c + 0) * NOFF], a0);
                a1 = fmaf(xp[c + 1], kp[(c + 1) * NOFF], a1);
                a2 = fmaf(xp[c + 2], kp[(c + 2) * NOFF], a2);
                a3 = fmaf(xp[c + 3], kp[(c + 3) * NOFF], a3);
            }
        }
        s_off[p][oc] = (a0 + a1) + (a2 + a3);
    }
    __syncthreads();

    // ---- phase 1: bilinear deformable sampling (lane = channel) ----
    {
        const float* basep = xin + (size_t)b * NH * NW * NC + lane;
        for (int kg = 0; kg < NKG; ++kg) {
            const int k  = kg >> 2;           // tap index; offset idx = k*NDG+g = kg
            const int ki = k / 3;
            const int kj = k - 3 * ki;
            float yv = (float)(oh + ki) + s_off[wv][kg * 2 + 0];
            float xv = (float)(ow + kj) + s_off[wv][kg * 2 + 1];
            yv = fminf(fmaxf(yv, 0.0f), PADMAXF);
            xv = fminf(fmaxf(xv, 0.0f), PADMAXF);
            const float y0f = floorf(yv), x0f = floorf(xv);
            const int y0 = (int)y0f, x0 = (int)x0f;
            const int y1 = min(y0 + 1, 57), x1 = min(x0 + 1, 57);
            const float ly = yv - y0f,       lx = xv - x0f;
            const float hy = (float)y1 - yv, hx = (float)x1 - xv;
            // padded coords valid iff 1..56 (pad ring = 0)
            const bool vy0 = (unsigned)(y0 - 1) < (unsigned)NH;
            const bool vy1 = (unsigned)(y1 - 1) < (unsigned)NH;
            const bool vx0 = (unsigned)(x0 - 1) < (unsigned)NW;
            const bool vx1 = (unsigned)(x1 - 1) < (unsigned)NW;
            float p00 = 0.0f, p01 = 0.0f, p10 = 0.0f, p11 = 0.0f;
            if (vy0 && vx0) p00 = basep[((y0 - 1) * NW + (x0 - 1)) * NC];
            if (vy0 && vx1) p01 = basep[((y0 - 1) * NW + (x1 - 1)) * NC];
            if (vy1 && vx0) p10 = basep[((y1 - 1) * NW + (x0 - 1)) * NC];
            if (vy1 && vx1) p11 = basep[((y1 - 1) * NW + (x1 - 1)) * NC];
            // exact reference weights (boundary y0==y1 -> both weights 0)
            s_pix[wv][kg][lane] = hy * hx * p00 + hy * lx * p01 +
                                  ly * hx * p10 + ly * lx * p11;
        }
    }
    __syncthreads();

    // ---- phase 2: grouped einsum (lane = output filter f; g = f>>4) ----
    {
        const int f = lane;
        const int g = f >> 4;
        float4 acc = make_float4(0.0f, 0.0f, 0.0f, 0.0f);
        for (int k = 0; k < NK; ++k) {
            const float4* wp = (const float4*)(wk + ((size_t)k * NF + f) * NC);
            const float4* pp = (const float4*)(&s_pix[wv][k * NDG + g][0]);
            #pragma unroll 4
            for (int c4 = 0; c4 < NC / 4; ++c4) {
                const float4 w4 = wp[c4];
                const float4 p4 = pp[c4];
                acc.x = fmaf(w4.x, p4.x, acc.x);
                acc.y = fmaf(w4.y, p4.y, acc.y);
                acc.z = fmaf(w4.z, p4.z, acc.z);
                acc.w = fmaf(w4.w, p4.w, acc.w);
            }
        }
        out[(size_t)pix * NF + f] = (acc.x + acc.y) + (acc.z + acc.w);
    }
}

extern "C" void kernel_launch(void* const* d_in, const int* in_sizes, int n_in,
                              void* d_out, int out_size, void* d_ws, size_t ws_size,
                              hipStream_t stream) {
    const float* xin  = (const float*)d_in[0];  // x            [4,56,56,64]
    const float* offk = (const float*)d_in[1];  // offset_kernel[3,3,64,72]
    const float* offb = (const float*)d_in[2];  // offset_bias  [72]
    const float* wk   = (const float*)d_in[3];  // kernel       [3,3,64,64]
    float* outp = (float*)d_out;                // [4,56,56,64] fp32

    const int nblocks = (NB * NH * NW) / PPB;   // 12544 / 4 = 3136
    dcn_fused<<<nblocks, 256, 0, stream>>>(xin, offk, offb, wk, outp);
}

// Round 2
// 209.047 us; speedup vs baseline: 1.9326x; 1.9326x over previous
//
#include <hip/hip_runtime.h>

// DeformableConv2D fused, round 2: latency-oriented restructure (fp32).
// Block = 64 threads = 1 wave; each wave owns P=4 consecutive pixels.
// LDS union region per block (9.28 KB):
//   phase 0 : s_x  [P][580]   (3x3x64 patch per pixel, padded stride)
//   phase 1+: s_off[P][72] at [0..288) , s_tap[P][4][68] at [288..1376)
// No cross-wave communication; __syncthreads() on a 1-wave block is a cheap
// wave-level memory fence (orders LDS role switches).

#define NB   4
#define NH   56
#define NW   56
#define NC   64
#define NDG  4
#define NK   9
#define NOFF 72
#define NF   64
#define P    4
#define SXS  580     // s_x per-pixel stride (576+4: p-groups 4 banks apart)
#define TAPB 288     // s_tap base (floats) within region
#define TSTR 68      // s_tap row stride: g-groups 4 banks apart

__global__ __launch_bounds__(64, 4)
void dcn_fused2(const float* __restrict__ xin,    // [4,56,56,64]
                const float* __restrict__ offk,   // [3,3,64,72]
                const float* __restrict__ offb,   // [72]
                const float* __restrict__ wk,     // [3,3,64,64] (k,f,c)
                float* __restrict__ out)          // [4,56,56,64]
{
    __shared__ float region[P * SXS];             // 2320 floats

    const int lane = threadIdx.x;                 // 0..63
    const int pix0 = blockIdx.x * P;

    int bb[P], oh[P], ow[P];
    #pragma unroll
    for (int p = 0; p < P; ++p) {
        const int pix = pix0 + p;
        bb[p] = pix / (NH * NW);
        const int rr = pix - bb[p] * (NH * NW);
        oh[p] = rr / NW;
        ow[p] = rr - oh[p] * NW;
    }

    // ---- stage 3x3 neighborhoods: lane = channel, coalesced ----
    #pragma unroll
    for (int p = 0; p < P; ++p) {
        #pragma unroll
        for (int t = 0; t < NK; ++t) {
            const int ih = oh[p] + t / 3 - 1;
            const int iw = ow[p] + t % 3 - 1;
            float v = 0.0f;
            if (ih >= 0 && ih < NH && iw >= 0 && iw < NW)
                v = xin[(((bb[p] * NH) + ih) * NW + iw) * NC + lane];
            region[p * SXS + t * NC + lane] = v;
        }
    }
    __syncthreads();

    // ---- phase 0: offset conv. Lane roles:
    //   main: oc = lane (0..63), all P pixels
    //   fold: oc2 = 64+(lane&7), pixel p2=(lane>>3)&3 (lanes 32..63 duplicate)
    const int oc2 = 64 + (lane & 7);
    const int p2  = (lane >> 3) & 3;
    float acc0 = offb[lane], acc1 = offb[lane], accA = offb[lane], accB = offb[lane];
    // distinct accumulators per pixel for ILP; acc order: p=0..3
    float a_p[P]; a_p[0] = acc0; a_p[1] = acc1; a_p[2] = accA; a_p[3] = accB;
    float a2 = offb[oc2];

    for (int t = 0; t < NK; ++t) {
        #pragma unroll 4
        for (int c4 = 0; c4 < NC / 4; ++c4) {
            const float4 xq0 = *(const float4*)&region[0 * SXS + t * NC + c4 * 4];
            const float4 xq1 = *(const float4*)&region[1 * SXS + t * NC + c4 * 4];
            const float4 xq2 = *(const float4*)&region[2 * SXS + t * NC + c4 * 4];
            const float4 xq3 = *(const float4*)&region[3 * SXS + t * NC + c4 * 4];
            const float4 xs  = *(const float4*)&region[p2 * SXS + t * NC + c4 * 4];
            const float* wp = offk + (size_t)(t * NC + c4 * 4) * NOFF;
            #pragma unroll
            for (int j = 0; j < 4; ++j) {
                const float w1 = wp[j * NOFF + lane];
                const float w2 = wp[j * NOFF + oc2];
                const float xj0 = (&xq0.x)[j], xj1 = (&xq1.x)[j];
                const float xj2 = (&xq2.x)[j], xj3 = (&xq3.x)[j];
                a_p[0] = fmaf(xj0, w1, a_p[0]);
                a_p[1] = fmaf(xj1, w1, a_p[1]);
                a_p[2] = fmaf(xj2, w1, a_p[2]);
                a_p[3] = fmaf(xj3, w1, a_p[3]);
                a2     = fmaf((&xs.x)[j], w2, a2);
            }
        }
    }
    __syncthreads();   // all s_x reads done before overwriting region with s_off

    // s_off layout: region[p*72 + oc], oc in [0,72)
    #pragma unroll
    for (int p = 0; p < P; ++p) region[p * NOFF + lane] = a_p[p];
    region[p2 * NOFF + oc2] = a2;   // duplicate lanes write identical values
    __syncthreads();

    // ---- phase 1+2 fused per tap ----
    float accF[P] = {0.0f, 0.0f, 0.0f, 0.0f};
    const int gf = lane >> 4;       // group of output filter f = lane

    for (int k = 0; k < NK; ++k) {
        const int ki = k / 3, kj = k - 3 * ki;

        // tap weights for f = lane, held in registers (64 VGPRs)
        float4 wreg[16];
        #pragma unroll
        for (int c4 = 0; c4 < NC / 4; ++c4)
            wreg[c4] = *(const float4*)&wk[((size_t)(k * NF) + lane) * NC + c4 * 4];

        // sampling: lane = channel
        #pragma unroll
        for (int p = 0; p < P; ++p) {
            const float* basep = xin + (size_t)bb[p] * NH * NW * NC + lane;
            #pragma unroll
            for (int g = 0; g < NDG; ++g) {
                const int kg = k * NDG + g;
                const float offy = region[p * NOFF + kg * 2 + 0];
                const float offx = region[p * NOFF + kg * 2 + 1];
                float yv = fminf(fmaxf((float)(oh[p] + ki) + offy, 0.0f), 57.0f);
                float xv = fminf(fmaxf((float)(ow[p] + kj) + offx, 0.0f), 57.0f);
                const float y0f = floorf(yv), x0f = floorf(xv);
                const int y0 = (int)y0f, x0 = (int)x0f;
                const int y1 = min(y0 + 1, 57), x1 = min(x0 + 1, 57);
                const float ly = yv - y0f,       lx = xv - x0f;
                const float hy = (float)y1 - yv, hx = (float)x1 - xv;
                const bool vy0 = (unsigned)(y0 - 1) < (unsigned)NH;
                const bool vy1 = (unsigned)(y1 - 1) < (unsigned)NH;
                const bool vx0 = (unsigned)(x0 - 1) < (unsigned)NW;
                const bool vx1 = (unsigned)(x1 - 1) < (unsigned)NW;
                float p00 = 0.0f, p01 = 0.0f, p10 = 0.0f, p11 = 0.0f;
                if (vy0 && vx0) p00 = basep[((y0 - 1) * NW + (x0 - 1)) * NC];
                if (vy0 && vx1) p01 = basep[((y0 - 1) * NW + (x1 - 1)) * NC];
                if (vy1 && vx0) p10 = basep[((y1 - 1) * NW + (x0 - 1)) * NC];
                if (vy1 && vx1) p11 = basep[((y1 - 1) * NW + (x1 - 1)) * NC];
                region[TAPB + (p * NDG + g) * TSTR + lane] =
                    hy * hx * p00 + hy * lx * p01 + ly * hx * p10 + ly * lx * p11;
            }
        }
        __syncthreads();

        // conv: lane = output filter f; pixels read broadcast from LDS
        #pragma unroll
        for (int p = 0; p < P; ++p) {
            const float* pp = &region[TAPB + (p * NDG + gf) * TSTR];
            #pragma unroll
            for (int c4 = 0; c4 < NC / 4; ++c4) {
                const float4 p4 = *(const float4*)&pp[c4 * 4];
                accF[p] = fmaf(wreg[c4].x, p4.x, accF[p]);
                accF[p] = fmaf(wreg[c4].y, p4.y, accF[p]);
                accF[p] = fmaf(wreg[c4].z, p4.z, accF[p]);
                accF[p] = fmaf(wreg[c4].w, p4.w, accF[p]);
            }
        }
        __syncthreads();   // conv reads done before next tap's sampling writes
    }

    #pragma unroll
    for (int p = 0; p < P; ++p)
        out[(size_t)(pix0 + p) * NF + lane] = accF[p];
}

extern "C" void kernel_launch(void* const* d_in, const int* in_sizes, int n_in,
                              void* d_out, int out_size, void* d_ws, size_t ws_size,
                              hipStream_t stream) {
    const float* xin  = (const float*)d_in[0];
    const float* offk = (const float*)d_in[1];
    const float* offb = (const float*)d_in[2];
    const float* wk   = (const float*)d_in[3];
    float* outp = (float*)d_out;

    const int nblocks = (NB * NH * NW) / P;   // 12544/4 = 3136 blocks of 64 thr
    dcn_fused2<<<nblocks, 64, 0, stream>>>(xin, offk, offb, wk, outp);
}

// Round 3
// 176.728 us; speedup vs baseline: 2.2861x; 1.1829x over previous
//
#include <hip/hip_runtime.h>

// DeformableConv2D fused via MFMA f16, round 3.
// P: weight prep (fp32 -> f16, offset weights transposed to [oc][K]).
// A: offset conv as MFMA GEMM  (M=12544 pix, N=80 (72 pad), K=576).
// B: bilinear sampling (fp32 VALU) + grouped conv as per-tap MFMA f16.
//
// MFMA 16x16x32 f16 layouts (m89/m120-verified):
//   A-frag: lane holds A[m=lane&15][k=(lane>>4)*8 + j], j=0..7  (16B contig)
//   B-frag: lane holds B[k=(lane>>4)*8 + j][n=lane&15]  -> store B as [n][k]
//   C/D  : col(n)=lane&15, row(m)=(lane>>4)*4 + reg

#define NB   4
#define NH   56
#define NW   56
#define NC   64
#define NDG  4
#define NK   9
#define NOFF 72
#define NOFFP 80      // N padded to 5 tiles of 16
#define NF   64
#define KTOT 576      // NK * NC
#define NPIX (NB * NH * NW)   // 12544
#define HWPIX (NH * NW)       // 3136

// d_ws layout (bytes)
#define WS_OFFKT 0                         // f16 [80][576]  = 92160 B
#define WS_WK    92160                     // f16 [9][64][64] = 73728 B
#define WS_OFFS  (92160 + 73728)           // f32 [12544][72] = 3612672 B

typedef _Float16 half8  __attribute__((ext_vector_type(8)));
typedef float    floatx4 __attribute__((ext_vector_type(4)));

__device__ __forceinline__ float uniformf(float v) {
    return __uint_as_float(__builtin_amdgcn_readfirstlane(__float_as_uint(v)));
}

// ---------------- P: weight conversion ----------------
__global__ __launch_bounds__(256)
void dcn_prep(const float* __restrict__ offk,   // [3,3,64,72]  (k,c,oc)
              const float* __restrict__ wk,     // [3,3,64,64]  (k,f,c)
              _Float16* __restrict__ offkt,     // [80][576]    (oc,k)
              _Float16* __restrict__ wkh)       // [9][64][64]
{
    const int i = blockIdx.x * 256 + threadIdx.x;
    if (i < NOFFP * KTOT) {
        const int oc = i / KTOT;
        const int k  = i - oc * KTOT;
        const float v = (oc < NOFF) ? offk[k * NOFF + oc] : 0.0f;
        offkt[i] = (_Float16)v;
    }
    const int j = i - NOFFP * KTOT;
    if (j >= 0 && j < NK * NF * NC) wkh[j] = (_Float16)wk[j];
}

// ---------------- A: offset conv GEMM ----------------
// block = 128 thr = 2 waves; 32 pixels/block; wave w = 16-pixel M-tile.
__global__ __launch_bounds__(128)
void dcn_offsets(const float* __restrict__ x,       // [4,56,56,64]
                 const _Float16* __restrict__ offkt,// [80][576]
                 const float* __restrict__ offb,    // [72]
                 float* __restrict__ offs)          // [12544][72]
{
    __shared__ __align__(16) _Float16 s_a[32 * 72];  // [m][72] f16, 144B rows

    const int tid  = threadIdx.x;
    const int w    = tid >> 6;
    const int lane = tid & 63;
    const int pix0 = blockIdx.x * 32;

    floatx4 acc[5];
    #pragma unroll
    for (int nt = 0; nt < 5; ++nt) {
        const int oc = nt * 16 + (lane & 15);
        const float bv = (oc < NOFF) ? offb[oc] : 0.0f;
        acc[nt] = (floatx4){bv, bv, bv, bv};
    }

    for (int k = 0; k < NK; ++k) {
        const int ki = k / 3, kj = k - 3 * ki;
        // stage this tap's [32 pix][64 c] slice as f16
        #pragma unroll
        for (int p = 0; p < 16; ++p) {
            const int pix = pix0 + w * 16 + p;
            const int b   = pix / HWPIX;
            const int rr  = pix - b * HWPIX;
            const int oh  = rr / NW, ow = rr - (rr / NW) * NW;
            const int ih  = oh + ki - 1, iw = ow + kj - 1;
            float v = 0.0f;
            if (ih >= 0 && ih < NH && iw >= 0 && iw < NW)
                v = x[(((b * NH) + ih) * NW + iw) * NC + lane];
            s_a[(w * 16 + p) * 72 + lane] = (_Float16)v;
        }
        __syncthreads();
        #pragma unroll
        for (int s = 0; s < 2; ++s) {
            const half8 af = *(const half8*)&s_a[(w * 16 + (lane & 15)) * 72 +
                                                 s * 32 + (lane >> 4) * 8];
            #pragma unroll
            for (int nt = 0; nt < 5; ++nt) {
                const half8 bf = *(const half8*)&offkt[(nt * 16 + (lane & 15)) * KTOT +
                                                       k * 64 + s * 32 + (lane >> 4) * 8];
                acc[nt] = __builtin_amdgcn_mfma_f32_16x16x32_f16(af, bf, acc[nt], 0, 0, 0);
            }
        }
        __syncthreads();
    }

    const int pixr = pix0 + w * 16 + (lane >> 4) * 4;
    #pragma unroll
    for (int nt = 0; nt < 5; ++nt) {
        const int oc = nt * 16 + (lane & 15);
        if (oc < NOFF) {
            #pragma unroll
            for (int r = 0; r < 4; ++r)
                offs[(size_t)(pixr + r) * NOFF + oc] = acc[nt][r];
        }
    }
}

// ---------------- B: sampling + grouped conv ----------------
// block = 256 thr = 4 waves; 16 pixels/block; wave w owns group g=w.
__global__ __launch_bounds__(256)
void dcn_main(const float* __restrict__ x,        // [4,56,56,64]
              const _Float16* __restrict__ wkh,   // [9][64][64] (k,f,c)
              const float* __restrict__ offs,     // [12544][72]
              float* __restrict__ out)            // [12544][64]
{
    __shared__ float s_off[16 * 72];
    __shared__ __align__(16) _Float16 s_a[4][16 * 72]; // [g][m][72] f16

    const int tid  = threadIdx.x;
    const int w    = tid >> 6;     // group
    const int lane = tid & 63;
    const int pix0 = blockIdx.x * 16;

    for (int i = tid; i < 16 * NOFF; i += 256)
        s_off[i] = offs[(size_t)pix0 * NOFF + i];
    __syncthreads();

    floatx4 acc = (floatx4){0.0f, 0.0f, 0.0f, 0.0f};

    for (int k = 0; k < NK; ++k) {
        const int ki = k / 3, kj = k - 3 * ki;
        // sample tap k for 16 pixels, group w; lane = channel
        #pragma unroll
        for (int p = 0; p < 16; ++p) {
            const int pix = pix0 + p;
            const int b   = pix / HWPIX;
            const int rr  = pix - b * HWPIX;
            const int oh  = rr / NW, ow = rr - (rr / NW) * NW;
            float offy = uniformf(s_off[p * NOFF + (k * NDG + w) * 2 + 0]);
            float offx = uniformf(s_off[p * NOFF + (k * NDG + w) * 2 + 1]);
            float yv = fminf(fmaxf((float)(oh + ki) + offy, 0.0f), 57.0f);
            float xv = fminf(fmaxf((float)(ow + kj) + offx, 0.0f), 57.0f);
            const float y0f = floorf(yv), x0f = floorf(xv);
            const int y0 = (int)y0f, x0 = (int)x0f;
            const int y1 = min(y0 + 1, 57), x1 = min(x0 + 1, 57);
            const float ly = yv - y0f,       lx = xv - x0f;
            const float hy = (float)y1 - yv, hx = (float)x1 - xv;
            const bool vy0 = (unsigned)(y0 - 1) < (unsigned)NH;
            const bool vy1 = (unsigned)(y1 - 1) < (unsigned)NH;
            const bool vx0 = (unsigned)(x0 - 1) < (unsigned)NW;
            const bool vx1 = (unsigned)(x1 - 1) < (unsigned)NW;
            const float* basep = x + (size_t)b * HWPIX * NC + lane;
            float p00 = 0.0f, p01 = 0.0f, p10 = 0.0f, p11 = 0.0f;
            if (vy0 && vx0) p00 = basep[((y0 - 1) * NW + (x0 - 1)) * NC];
            if (vy0 && vx1) p01 = basep[((y0 - 1) * NW + (x1 - 1)) * NC];
            if (vy1 && vx0) p10 = basep[((y1 - 1) * NW + (x0 - 1)) * NC];
            if (vy1 && vx1) p11 = basep[((y1 - 1) * NW + (x1 - 1)) * NC];
            const float val = hy * hx * p00 + hy * lx * p01 +
                              ly * hx * p10 + ly * lx * p11;
            s_a[w][p * 72 + lane] = (_Float16)val;
        }
        __syncthreads();
        // grouped conv: A = s_a[w] (16 pix x 64 c), B = wkh[k][f=w*16..][c]
        #pragma unroll
        for (int s = 0; s < 2; ++s) {
            const half8 af = *(const half8*)&s_a[w][(lane & 15) * 72 +
                                                    s * 32 + (lane >> 4) * 8];
            const half8 bf = *(const half8*)&wkh[((size_t)(k * NF) + w * 16 + (lane & 15)) * NC +
                                                 s * 32 + (lane >> 4) * 8];
            acc = __builtin_amdgcn_mfma_f32_16x16x32_f16(af, bf, acc, 0, 0, 0);
        }
        __syncthreads();
    }

    const int pixr = pix0 + (lane >> 4) * 4;
    #pragma unroll
    for (int r = 0; r < 4; ++r)
        out[(size_t)(pixr + r) * NF + w * 16 + (lane & 15)] = acc[r];
}

extern "C" void kernel_launch(void* const* d_in, const int* in_sizes, int n_in,
                              void* d_out, int out_size, void* d_ws, size_t ws_size,
                              hipStream_t stream) {
    const float* xin  = (const float*)d_in[0];
    const float* offk = (const float*)d_in[1];
    const float* offb = (const float*)d_in[2];
    const float* wk   = (const float*)d_in[3];
    float* outp = (float*)d_out;

    _Float16* offkt = (_Float16*)((char*)d_ws + WS_OFFKT);
    _Float16* wkh   = (_Float16*)((char*)d_ws + WS_WK);
    float*    offs  = (float*)   ((char*)d_ws + WS_OFFS);

    // P: (80*576 + 9*64*64) = 82944 elements -> 324 blocks
    dcn_prep<<<324, 256, 0, stream>>>(offk, wk, offkt, wkh);
    // A: 12544/32 = 392 blocks x 128 thr
    dcn_offsets<<<392, 128, 0, stream>>>(xin, offkt, offb, offs);
    // B: 12544/16 = 784 blocks x 256 thr
    dcn_main<<<784, 256, 0, stream>>>(xin, wkh, offs, outp);
}

// Round 4
// 114.951 us; speedup vs baseline: 3.5146x; 1.5374x over previous
//
#include <hip/hip_runtime.h>

// DeformableConv2D round 4: single fused MFMA kernel + tiny weight-prep.
//
// prep: offset weights -> f16 transposed [80][576]; conv weights -> f16.
// main: 784 blocks x 256 thr (4 waves), 16 pixels/block.
//   A : offset conv as MFMA GEMM, A-frags gathered straight from global x
//       (per-lane predicated loads, f16 cvt in regs). Waves split the 5
//       N-tiles (wave 3 takes tiles 3 and 4). ZERO barriers.
//   A': coord/weight table, lane = sample (576 items / 256 thr) -- per-sample
//       scalar math issued once, not 64-wide redundantly. Ring corners get
//       weight 0 (== reference's zero-padded gather); addresses clamped.
//   B : per tap: 4 gathers + weighted sum + f16 pack -> s_sa[w], then 2 MFMAs.
//       Wave w only touches s_sa[w] => NO barriers in the tap loop.
// Barriers per block: 2.
//
// MFMA 16x16x32 f16 layouts (verified by rounds 3's passing run):
//   A-frag: lane holds A[m=lane&15][k=(lane>>4)*8+j]
//   B-frag: lane holds B[k=(lane>>4)*8+j][n=lane&15]   (B stored [n][k])
//   C/D  : col(n)=lane&15, row(m)=(lane>>4)*4+reg

#define NH 56
#define NW 56
#define NC 64
#define NDG 4
#define NK 9
#define NOFF 72
#define NOFFP 80
#define NF 64
#define KTOT 576
#define HWPIX 3136
#define NPIX 12544

#define WS_OFFKT 0          // f16 [80][576]   = 92160 B
#define WS_WK    92160      // f16 [9][64][64] = 73728 B

typedef _Float16 half8   __attribute__((ext_vector_type(8)));
typedef float    floatx4 __attribute__((ext_vector_type(4)));

// ---------------- prep: weight conversion ----------------
__global__ __launch_bounds__(256)
void dcn_prep(const float* __restrict__ offk,   // [3,3,64,72] (kk,oc)
              const float* __restrict__ wk,     // [3,3,64,64] (k,f,c)
              _Float16* __restrict__ offkt,     // [80][576]   (oc,kk)
              _Float16* __restrict__ wkh)       // [9][64][64]
{
    const int i = blockIdx.x * 256 + threadIdx.x;
    if (i < NOFFP * KTOT) {
        const int oc = i / KTOT;
        const int kk = i - oc * KTOT;
        const float v = (oc < NOFF) ? offk[kk * NOFF + oc] : 0.0f;
        offkt[i] = (_Float16)v;
    }
    const int j = i - NOFFP * KTOT;
    if (j >= 0 && j < NK * NF * NC) wkh[j] = (_Float16)wk[j];
}

// ---------------- fused main ----------------
__global__ __launch_bounds__(256, 4)
void dcn_main(const float* __restrict__ x,        // [4,56,56,64]
              const _Float16* __restrict__ offkt, // [80][576]
              const float* __restrict__ offb,     // [72]
              const _Float16* __restrict__ wkh,   // [9][64][64]
              float* __restrict__ out)            // [12544][64]
{
    __shared__ float s_off[16 * NOFF];                    // 4.6 KB
    __shared__ __align__(16) float s_cww[576 * 4];        // 9.2 KB
    __shared__ __align__(16) int   s_cwi[576 * 4];        // 9.2 KB
    __shared__ __align__(16) _Float16 s_sa[4][16 * 72];   // 9.2 KB

    const int tid  = threadIdx.x;
    const int w    = tid >> 6;      // wave id: A = N-tile, B = group
    const int lane = tid & 63;
    const int m    = lane & 15;     // MFMA row / col index
    const int kq   = lane >> 4;     // MFMA k-quad

    const int pix0 = blockIdx.x * 16;
    const int pixm = pix0 + m;
    const int bm   = pixm / HWPIX;
    const int rrm  = pixm - bm * HWPIX;
    const int ohm  = rrm / NW;
    const int owm  = rrm - ohm * NW;
    const float* xbase = x + (size_t)(bm * HWPIX + ohm * NW + owm) * NC + kq * 8;

    // ---- phase A: offset conv GEMM, zero barriers ----
    const int oc0 = w * 16 + m;     // 0..63
    floatx4 acc0, acc1;
    { const float bv = offb[oc0]; acc0 = (floatx4){bv, bv, bv, bv}; }
    { const float bv = (w == 3 && m < 8) ? offb[64 + m] : 0.0f;
      acc1 = (floatx4){bv, bv, bv, bv}; }

    #pragma unroll
    for (int k = 0; k < NK; ++k) {
        const int ki = k / 3, kj = k - 3 * ki;
        const int ih = ohm + ki - 1, iw = owm + kj - 1;
        const bool vld = ((unsigned)ih < NH) && ((unsigned)iw < NW);
        const float* ap = xbase + ((ki - 1) * NW + (kj - 1)) * NC;
        #pragma unroll
        for (int s = 0; s < 2; ++s) {
            float4 a0 = make_float4(0.f, 0.f, 0.f, 0.f), a1 = a0;
            if (vld) {
                a0 = *(const float4*)(ap + s * 32);
                a1 = *(const float4*)(ap + s * 32 + 4);
            }
            half8 af;
            af[0] = (_Float16)a0.x; af[1] = (_Float16)a0.y;
            af[2] = (_Float16)a0.z; af[3] = (_Float16)a0.w;
            af[4] = (_Float16)a1.x; af[5] = (_Float16)a1.y;
            af[6] = (_Float16)a1.z; af[7] = (_Float16)a1.w;
            const int kkb = k * 64 + s * 32 + kq * 8;
            const half8 bf0 = *(const half8*)&offkt[(size_t)oc0 * KTOT + kkb];
            acc0 = __builtin_amdgcn_mfma_f32_16x16x32_f16(af, bf0, acc0, 0, 0, 0);
            if (w == 3) {
                const half8 bf1 = *(const half8*)&offkt[(size_t)(64 + m) * KTOT + kkb];
                acc1 = __builtin_amdgcn_mfma_f32_16x16x32_f16(af, bf1, acc1, 0, 0, 0);
            }
        }
    }
    #pragma unroll
    for (int r = 0; r < 4; ++r)
        s_off[(kq * 4 + r) * NOFF + oc0] = acc0[r];
    if (w == 3 && m < 8) {
        #pragma unroll
        for (int r = 0; r < 4; ++r)
            s_off[(kq * 4 + r) * NOFF + 64 + m] = acc1[r];
    }
    __syncthreads();

    // ---- phase A': coord/weight table, lane = sample ----
    for (int i = tid; i < 16 * 36; i += 256) {
        const int p  = i / 36;
        const int kg = i - p * 36;              // k*NDG + g
        const int k  = kg >> 2;
        const int ki = k / 3, kj = k - 3 * ki;
        const int pix = pix0 + p;
        const int b   = pix / HWPIX;
        const int rr  = pix - b * HWPIX;
        const int oh  = rr / NW, ow = rr - (rr / NW) * NW;
        const float offy = s_off[p * NOFF + kg * 2 + 0];
        const float offx = s_off[p * NOFF + kg * 2 + 1];
        float yv = fminf(fmaxf((float)(oh + ki) + offy, 0.0f), 57.0f);
        float xv = fminf(fmaxf((float)(ow + kj) + offx, 0.0f), 57.0f);
        const float y0f = floorf(yv), x0f = floorf(xv);
        const int y0 = (int)y0f, x0 = (int)x0f;
        const int y1 = min(y0 + 1, 57), x1 = min(x0 + 1, 57);
        const float ly = yv - y0f,       lx = xv - x0f;
        const float hy = (float)y1 - yv, hx = (float)x1 - xv;
        const bool vy0 = (unsigned)(y0 - 1) < NH;
        const bool vy1 = (unsigned)(y1 - 1) < NH;
        const bool vx0 = (unsigned)(x0 - 1) < NW;
        const bool vx1 = (unsigned)(x1 - 1) < NW;
        const float w00 = (vy0 && vx0) ? hy * hx : 0.0f;
        const float w01 = (vy0 && vx1) ? hy * lx : 0.0f;
        const float w10 = (vy1 && vx0) ? ly * hx : 0.0f;
        const float w11 = (vy1 && vx1) ? ly * lx : 0.0f;
        const int y0c = min(max(y0 - 1, 0), NH - 1);
        const int y1c = min(max(y1 - 1, 0), NH - 1);
        const int x0c = min(max(x0 - 1, 0), NW - 1);
        const int x1c = min(max(x1 - 1, 0), NW - 1);
        const int bb = b * HWPIX;
        *(float4*)&s_cww[i * 4] = make_float4(w00, w01, w10, w11);
        *(int4*)&s_cwi[i * 4]   = make_int4((bb + y0c * NW + x0c) * NC,
                                            (bb + y0c * NW + x1c) * NC,
                                            (bb + y1c * NW + x0c) * NC,
                                            (bb + y1c * NW + x1c) * NC);
    }
    __syncthreads();

    // ---- phase B: sampling + grouped conv, zero barriers ----
    floatx4 accB = (floatx4){0.f, 0.f, 0.f, 0.f};
    _Float16* sa = &s_sa[w][0];
    #pragma unroll 1
    for (int k = 0; k < NK; ++k) {
        #pragma unroll 8
        for (int p = 0; p < 16; ++p) {
            const int i = (p * 36 + k * 4 + w) * 4;
            const float4 cw = *(const float4*)&s_cww[i];
            const int4  ci = *(const int4*)&s_cwi[i];
            float v =       cw.x * x[ci.x + lane];
            v = fmaf(cw.y, x[ci.y + lane], v);
            v = fmaf(cw.z, x[ci.z + lane], v);
            v = fmaf(cw.w, x[ci.w + lane], v);
            sa[p * 72 + lane] = (_Float16)v;
        }
        #pragma unroll
        for (int s = 0; s < 2; ++s) {
            const half8 af = *(const half8*)&sa[m * 72 + s * 32 + kq * 8];
            const half8 bf = *(const half8*)&wkh[(size_t)(k * NF + w * 16 + m) * NC +
                                                 s * 32 + kq * 8];
            accB = __builtin_amdgcn_mfma_f32_16x16x32_f16(af, bf, accB, 0, 0, 0);
        }
    }

    #pragma unroll
    for (int r = 0; r < 4; ++r)
        out[(size_t)(pix0 + kq * 4 + r) * NF + w * 16 + m] = accB[r];
}

extern "C" void kernel_launch(void* const* d_in, const int* in_sizes, int n_in,
                              void* d_out, int out_size, void* d_ws, size_t ws_size,
                              hipStream_t stream) {
    const float* xin  = (const float*)d_in[0];
    const float* offk = (const float*)d_in[1];
    const float* offb = (const float*)d_in[2];
    const float* wk   = (const float*)d_in[3];
    float* outp = (float*)d_out;

    _Float16* offkt = (_Float16*)((char*)d_ws + WS_OFFKT);
    _Float16* wkh   = (_Float16*)((char*)d_ws + WS_WK);

    dcn_prep<<<324, 256, 0, stream>>>(offk, wk, offkt, wkh);
    dcn_main<<<NPIX / 16, 256, 0, stream>>>(xin, offkt, offb, wkh, outp);
}